// Round 1
// baseline (1053.391 us; speedup 1.0000x reference)
//
#include <hip/hip_runtime.h>

#define MDIM 8192
#define KDIM 32
#define JT 256            // j-tile per LDS stage (= blockDim)
#define SROW 260          // LDS row stride in floats (16B-aligned, conflict-free)
#define TILES (MDIM / JT) // 32
#define RPW 4             // rows per wave
#define ROWS_PER_BLOCK 16 // 4 waves * 4 rows
#define NBLOCKS (MDIM / ROWS_PER_BLOCK) // 512

__global__ __launch_bounds__(256, 2)
void spectral_main(const float* __restrict__ W, const float* __restrict__ Y,
                   float* __restrict__ ws) {
    __shared__ float YT[KDIM * SROW];  // 33,280 B, transposed Y tile: YT[k][j_local]

    const int tid  = threadIdx.x;
    const int wave = tid >> 6;
    const int lane = tid & 63;
    const int rowBase = blockIdx.x * ROWS_PER_BLOCK + wave * RPW;
    const int jl = 4 * lane;           // lane's j offset within tile

    const float* Wr[RPW];
#pragma unroll
    for (int t = 0; t < RPW; ++t) Wr[t] = W + (size_t)(rowBase + t) * MDIM;

    float acc[RPW][KDIM];
#pragma unroll
    for (int t = 0; t < RPW; ++t)
#pragma unroll
        for (int k = 0; k < KDIM; ++k) acc[t][k] = 0.f;
    float accd[RPW] = {0.f, 0.f, 0.f, 0.f};

    // Staging registers: thread stages global row j = tile*JT + tid (32 floats)
    const float4* Yv = (const float4*)Y;   // Y[j][4q] -> Yv[j*8 + q]
    float4 yreg[8];
#pragma unroll
    for (int q = 0; q < 8; ++q) yreg[q] = Yv[(size_t)tid * 8 + q];

    float4 wcur[RPW], wnext[RPW];
#pragma unroll
    for (int t = 0; t < RPW; ++t) wcur[t] = *(const float4*)(Wr[t] + jl);

    for (int tile = 0; tile < TILES; ++tile) {
        __syncthreads();   // previous compute done reading LDS
        // transpose-write staged tile: YT[k][tid] = Y[tile*JT + tid][k]
#pragma unroll
        for (int q = 0; q < 8; ++q) {
            YT[(4 * q + 0) * SROW + tid] = yreg[q].x;
            YT[(4 * q + 1) * SROW + tid] = yreg[q].y;
            YT[(4 * q + 2) * SROW + tid] = yreg[q].z;
            YT[(4 * q + 3) * SROW + tid] = yreg[q].w;
        }
        __syncthreads();   // YT visible (lgkm drain only; no vmem outstanding here)

        // Prefetch next tile (consumed after the next barrier pair -> latency hidden)
        if (tile + 1 < TILES) {
#pragma unroll
            for (int q = 0; q < 8; ++q)
                yreg[q] = Yv[(size_t)((tile + 1) * JT + tid) * 8 + q];
            const int joff = (tile + 1) * JT + jl;
#pragma unroll
            for (int t = 0; t < RPW; ++t) wnext[t] = *(const float4*)(Wr[t] + joff);
        }

        // Compute: 32 ds_read_b128 + 512 FMA per lane
#pragma unroll
        for (int k = 0; k < KDIM; ++k) {
            float4 y4 = *(const float4*)&YT[k * SROW + jl];
#pragma unroll
            for (int t = 0; t < RPW; ++t) {
                acc[t][k] += wcur[t].x * y4.x;
                acc[t][k] += wcur[t].y * y4.y;
                acc[t][k] += wcur[t].z * y4.z;
                acc[t][k] += wcur[t].w * y4.w;
            }
        }
#pragma unroll
        for (int t = 0; t < RPW; ++t)
            accd[t] += (wcur[t].x + wcur[t].y) + (wcur[t].z + wcur[t].w);

        if (tile + 1 < TILES) {
#pragma unroll
            for (int t = 0; t < RPW; ++t) wcur[t] = wnext[t];
        }
    }

    // Epilogue: per row, s = Y_row . WY_row (linear in lane partials), d = row sum
    float contrib = 0.f;
#pragma unroll
    for (int t = 0; t < RPW; ++t) {
        const float* Yrow = Y + (size_t)(rowBase + t) * KDIM;
        float s = 0.f;
#pragma unroll
        for (int k = 0; k < KDIM; ++k) s += Yrow[k] * acc[t][k];
        float d = accd[t];
#pragma unroll
        for (int off = 32; off > 0; off >>= 1) {
            s += __shfl_xor(s, off);
            d += __shfl_xor(d, off);
        }
        float yy = 0.f;
#pragma unroll
        for (int k = 0; k < KDIM; ++k) yy += Yrow[k] * Yrow[k];
        contrib += yy - s / d;
    }
    if (lane == 0) atomicAdd(ws, contrib);
}

__global__ void zero_ws_kernel(float* ws) { ws[0] = 0.f; }

__global__ void finalize_kernel(const float* __restrict__ ws, float* __restrict__ out) {
    out[0] = ws[0] / (float)MDIM;
}

extern "C" void kernel_launch(void* const* d_in, const int* in_sizes, int n_in,
                              void* d_out, int out_size, void* d_ws, size_t ws_size,
                              hipStream_t stream) {
    const float* W = (const float*)d_in[0];
    const float* Y = (const float*)d_in[1];
    float* out = (float*)d_out;
    float* ws  = (float*)d_ws;

    zero_ws_kernel<<<1, 1, 0, stream>>>(ws);
    spectral_main<<<NBLOCKS, 256, 0, stream>>>(W, Y, ws);
    finalize_kernel<<<1, 1, 0, stream>>>(ws, out);
}